// Round 1
// baseline (653.647 us; speedup 1.0000x reference)
//
#include <hip/hip_runtime.h>

#define S 2048
#define D 1024
#define H 16
#define HD 64

typedef _Float16 half8 __attribute__((ext_vector_type(8)));
typedef _Float16 half4v __attribute__((ext_vector_type(4)));
typedef float f32x4 __attribute__((ext_vector_type(4)));

__device__ __forceinline__ float fast_exp2(float x) {
#if __has_builtin(__builtin_amdgcn_exp2f)
    return __builtin_amdgcn_exp2f(x);
#else
    return exp2f(x);
#endif
}

// ---------------------------------------------------------------------------
// K1: fp32 -> fp16 elementwise convert (range-safe: |enc|<~6, |W|<~0.2)
// ---------------------------------------------------------------------------
__global__ __launch_bounds__(256) void cvt_f32_f16(const float* __restrict__ src,
                                                   _Float16* __restrict__ dst, int n4) {
    const int i = blockIdx.x * 256 + threadIdx.x;
    if (i >= n4) return;
    const float4 v = ((const float4*)src)[i];
    half4v h;
    h.x = (_Float16)v.x; h.y = (_Float16)v.y;
    h.z = (_Float16)v.z; h.w = (_Float16)v.w;
    ((half4v*)dst)[i] = h;
}

// ---------------------------------------------------------------------------
// K2: proj GEMM, fp16 MFMA. C[m,e] = sum_d enc[m,d]*W[e,d] (+bias, split q/k).
// 128x128 tile, BK=32, 4 waves each 64x64 (4x4 tiles of 16x16x32).
// K rows are pre-scaled by (1/8)*log2(e) so attn scores come out in the
// exp2 domain: softmax p = exp2(score)/sum(exp2) == exp(s)/sum(exp(s)).
// ---------------------------------------------------------------------------
__global__ __launch_bounds__(256) void proj_mfma(const _Float16* __restrict__ Ah,  // [4096][1024]
                                                 const _Float16* __restrict__ Wh,  // [2048][1024]
                                                 const float* __restrict__ bias,
                                                 _Float16* __restrict__ qbuf,     // [32][2048][64]
                                                 _Float16* __restrict__ kbuf) {
    __shared__ __align__(16) _Float16 As[4][128][8];   // 8 KB
    __shared__ __align__(16) _Float16 Bs[4][128][8];   // 8 KB
    const int tid = threadIdx.x;
    const int w   = tid >> 6;
    const int l   = tid & 63;
    const int l15 = l & 15;
    const int l4  = l >> 4;
    const int wy  = w >> 1;        // 0,1 : row half
    const int wx  = w & 1;         // 0,1 : col half
    const int m0  = blockIdx.x * 128;
    const int n0  = blockIdx.y * 128;

    f32x4 acc[4][4] = {};

    for (int k0 = 0; k0 < D; k0 += 32) {
        if (k0) __syncthreads();
        #pragma unroll
        for (int p = 0; p < 2; ++p) {
            const int slot = p * 256 + tid;
            const int sub = slot >> 7, row = slot & 127;
            *(uint4*)&As[sub][row][0] = *(const uint4*)(Ah + (size_t)(m0 + row) * D + k0 + sub * 8);
            *(uint4*)&Bs[sub][row][0] = *(const uint4*)(Wh + (size_t)(n0 + row) * D + k0 + sub * 8);
        }
        __syncthreads();

        half8 af[4], bf[4];
        #pragma unroll
        for (int i = 0; i < 4; ++i)
            af[i] = *(const half8*)&As[l4][wy * 64 + i * 16 + l15][0];
        #pragma unroll
        for (int j = 0; j < 4; ++j)
            bf[j] = *(const half8*)&Bs[l4][wx * 64 + j * 16 + l15][0];
        #pragma unroll
        for (int i = 0; i < 4; ++i)
            #pragma unroll
            for (int j = 0; j < 4; ++j)
                acc[i][j] = __builtin_amdgcn_mfma_f32_16x16x32_f16(af[i], bf[j], acc[i][j], 0, 0, 0);
    }

    // epilogue: e-column = n0 + wx*64 + j*16 + l15 ; m-row = m0 + wy*64 + i*16 + l4*4 + r
    #pragma unroll
    for (int j = 0; j < 4; ++j) {
        const int e   = n0 + wx * 64 + j * 16 + l15;
        const bool isq = (e < D);
        const int eh  = isq ? e : (e - D);
        const int h   = eh >> 6;
        const int hd  = eh & 63;
        _Float16* dst = isq ? qbuf : kbuf;
        const float sc = isq ? 1.0f : 0.18033688f;   // (1/8)*log2(e)
        const float bv = bias[e];
        #pragma unroll
        for (int i = 0; i < 4; ++i) {
            #pragma unroll
            for (int r = 0; r < 4; ++r) {
                const int m  = m0 + wy * 64 + i * 16 + l4 * 4 + r;
                const int bb = m >> 11;             // m / S
                const int ss = m & (S - 1);
                dst[((size_t)(bb * H + h) * S + ss) * HD + hd] = (_Float16)((acc[i][j][r] + bv) * sc);
            }
        }
    }
}

// ---------------------------------------------------------------------------
// K3: fused scores + causal softmax, no-LDS / no-barrier / no-max version.
//  - scores are bounded (|s|~<6 sigma): softmax without max-subtraction is
//    exact in fp32, so pass A only accumulates sum(exp2(score)) in registers.
//  - K fragments are loaded half8 straight from global (K slice = 256 KB,
//    L2-resident); no __syncthreads anywhere.
//  - 1-D grid of 1024 decoded so each XCD owns 4 heads (2 MB working set)
//    and each CU's 4 resident blocks have stripe weights summing to a
//    constant 66 tile-iters -> perfect static balance of compute AND writes.
//  - all output stores nontemporal (512 MiB stream must not evict K/Q).
// ---------------------------------------------------------------------------
__global__ __launch_bounds__(256) void attn_fused(const _Float16* __restrict__ qbuf,
                                                  const _Float16* __restrict__ kbuf,
                                                  float* __restrict__ out) {
    const int tid = threadIdx.x;
    const int w   = tid >> 6;
    const int l   = tid & 63;
    const int l15 = l & 15;
    const int l4  = l >> 4;

    // block remap: bid -> (z, t-stripe)
    const int bid  = blockIdx.x;        // 0..1023
    const int xcd  = bid & 7;
    const int slot = bid >> 3;          // 0..127
    const int k    = slot >> 5;         // 0..3 : which of this XCD's 4 heads
    int tsr = slot & 31;
    if (k & 2) tsr = (tsr + 16) & 31;
    const int ts = (k & 1) ? (31 - tsr) : tsr;   // stripe 0..31, CU-balanced
    const int z  = xcd * 4 + k;                  // 0..31 = b*H+h
    const int t0 = ts * 64;

    const _Float16* Qg = qbuf + (size_t)z * S * HD;
    const _Float16* Kg = kbuf + (size_t)z * S * HD;
    float* outz = out + (size_t)z * S * S;

    // Q fragments: rows t0 + w*16 + l15, halfs [l4*8, +8) and [32+l4*8, +8)
    const _Float16* qrow = Qg + (size_t)(t0 + w * 16 + l15) * HD + l4 * 8;
    const half8 qf0 = *(const half8*)qrow;
    const half8 qf1 = *(const half8*)(qrow + 32);

    const int nst  = ts + 1;
    const int trow = t0 + w * 16 + l4 * 4;
    const _Float16* kbase = Kg + (size_t)l15 * HD + l4 * 8;

    float sum_r[4] = {0.f, 0.f, 0.f, 0.f};

    // ---------------- PASS A: row sums of exp2(score) ----------------
    for (int st = 0; st < nst; ++st) {
        const _Float16* kp = kbase + (size_t)st * (64 * HD);
        f32x4 c[4] = {};
        #pragma unroll
        for (int j = 0; j < 4; ++j) {
            const half8 kf0 = *(const half8*)(kp + j * (16 * HD));
            const half8 kf1 = *(const half8*)(kp + j * (16 * HD) + 32);
            c[j] = __builtin_amdgcn_mfma_f32_16x16x32_f16(qf0, kf0, c[j], 0, 0, 0);
            c[j] = __builtin_amdgcn_mfma_f32_16x16x32_f16(qf1, kf1, c[j], 0, 0, 0);
        }
        if (st == ts) {   // diagonal tile: mask s > t
            #pragma unroll
            for (int j = 0; j < 4; ++j) {
                const int scol = t0 + j * 16 + l15;
                #pragma unroll
                for (int r = 0; r < 4; ++r)
                    if (scol > trow + r) c[j][r] = -1e30f;   // exp2 -> exact 0
            }
        }
        #pragma unroll
        for (int j = 0; j < 4; ++j)
            #pragma unroll
            for (int r = 0; r < 4; ++r)
                sum_r[r] += fast_exp2(c[j][r]);
    }

    // single cross-lane reduce per block (16-lane groups share rows)
    float inv_l[4];
    #pragma unroll
    for (int r = 0; r < 4; ++r) {
        float s = sum_r[r];
        s += __shfl_xor(s, 1, 16);
        s += __shfl_xor(s, 2, 16);
        s += __shfl_xor(s, 4, 16);
        s += __shfl_xor(s, 8, 16);
        inv_l[r] = 1.0f / s;
    }

    // ---------------- PASS B: recompute + write ----------------
    float* wrow = outz + (size_t)trow * S + l15;
    for (int st = 0; st < nst; ++st) {
        const int s0 = st * 64;
        const _Float16* kp = kbase + (size_t)st * (64 * HD);
        f32x4 c[4] = {};
        #pragma unroll
        for (int j = 0; j < 4; ++j) {
            const half8 kf0 = *(const half8*)(kp + j * (16 * HD));
            const half8 kf1 = *(const half8*)(kp + j * (16 * HD) + 32);
            c[j] = __builtin_amdgcn_mfma_f32_16x16x32_f16(qf0, kf0, c[j], 0, 0, 0);
            c[j] = __builtin_amdgcn_mfma_f32_16x16x32_f16(qf1, kf1, c[j], 0, 0, 0);
        }
        if (st == ts) {
            #pragma unroll
            for (int j = 0; j < 4; ++j) {
                const int scol = t0 + j * 16 + l15;
                #pragma unroll
                for (int r = 0; r < 4; ++r)
                    if (scol > trow + r) c[j][r] = -1e30f;
            }
        }
        #pragma unroll
        for (int r = 0; r < 4; ++r) {
            float* rowp = wrow + (size_t)r * S + s0;
            #pragma unroll
            for (int j = 0; j < 4; ++j)
                __builtin_nontemporal_store(fast_exp2(c[j][r]) * inv_l[r], rowp + j * 16);
        }
    }

    // ---------------- zero-fill upper-triangle rectangle ----------------
    const int zc0 = t0 + 64;            // cols [zc0, S) are zero for all 64 rows
    if (zc0 < S) {
        const int W4 = (S - zc0) >> 2;
        const f32x4 z4 = {0.f, 0.f, 0.f, 0.f};
        for (int row = w; row < 64; row += 4) {       // per-wave rows: no barrier needed
            float* rp = outz + (size_t)(t0 + row) * S + zc0;
            for (int c4 = l; c4 < W4; c4 += 64)
                __builtin_nontemporal_store(z4, (f32x4*)(rp + c4 * 4));
        }
    }
}

extern "C" void kernel_launch(void* const* d_in, const int* in_sizes, int n_in,
                              void* d_out, int out_size, void* d_ws, size_t ws_size,
                              hipStream_t stream) {
    const float* enc  = (const float*)d_in[0];   // (2,2048,1024) fp32
    const float* Wf   = (const float*)d_in[1];   // (2048,1024)   fp32
    const float* bias = (const float*)d_in[2];   // (2048,)       fp32
    float* out = (float*)d_out;                  // (2,16,2048,2048) fp32

    _Float16* enc_h = (_Float16*)d_ws;                       // 4,194,304 elems
    _Float16* w_h   = enc_h + (size_t)4096 * 1024;           // 2,097,152
    _Float16* qbuf  = w_h   + (size_t)2048 * 1024;           // 4,194,304
    _Float16* kbuf  = qbuf  + (size_t)32 * 2048 * 64;        // 4,194,304

    const int n4_enc = (4096 * 1024) / 4;
    const int n4_w   = (2048 * 1024) / 4;
    cvt_f32_f16<<<(n4_enc + 255) / 256, 256, 0, stream>>>(enc, enc_h, n4_enc);
    cvt_f32_f16<<<(n4_w   + 255) / 256, 256, 0, stream>>>(Wf, w_h, n4_w);

    proj_mfma<<<dim3(4096 / 128, 2048 / 128), 256, 0, stream>>>(enc_h, w_h, bias, qbuf, kbuf);

    attn_fused<<<dim3(1024), 256, 0, stream>>>(qbuf, kbuf, out);
}

// Round 2
// 635.299 us; speedup vs baseline: 1.0289x; 1.0289x over previous
//
#include <hip/hip_runtime.h>

#define S 2048
#define D 1024
#define H 16
#define HD 64

typedef _Float16 half8 __attribute__((ext_vector_type(8)));
typedef _Float16 half4v __attribute__((ext_vector_type(4)));
typedef float f32x4 __attribute__((ext_vector_type(4)));

__device__ __forceinline__ float fast_exp2(float x) {
#if __has_builtin(__builtin_amdgcn_exp2f)
    return __builtin_amdgcn_exp2f(x);
#else
    return exp2f(x);
#endif
}

#if __has_builtin(__builtin_amdgcn_global_load_lds)
#define HAVE_GLDS 1
#define GLDS16(gsrc, ldst)                                                     \
    __builtin_amdgcn_global_load_lds(                                          \
        (const __attribute__((address_space(1))) unsigned int*)(gsrc),         \
        (__attribute__((address_space(3))) unsigned int*)(ldst), 16, 0, 0)
#else
#define HAVE_GLDS 0
#endif

// ---------------------------------------------------------------------------
// K1: fused fp32 -> fp16 convert of BOTH enc and W (one launch).
// ---------------------------------------------------------------------------
#define N4_ENC (4096 * 1024 / 4)
#define N4_W   (2048 * 1024 / 4)

__global__ __launch_bounds__(256) void cvt_both(const float* __restrict__ enc,
                                                const float* __restrict__ Wf,
                                                _Float16* __restrict__ enc_h,
                                                _Float16* __restrict__ w_h) {
    const int i = blockIdx.x * 256 + threadIdx.x;
    const float* src;
    _Float16* dst;
    int j;
    if (i < N4_ENC) { src = enc; dst = enc_h; j = i; }
    else            { src = Wf;  dst = w_h;   j = i - N4_ENC; }
    const float4 v = ((const float4*)src)[j];
    half4v h;
    h.x = (_Float16)v.x; h.y = (_Float16)v.y;
    h.z = (_Float16)v.z; h.w = (_Float16)v.w;
    ((half4v*)dst)[j] = h;
}

// ---------------------------------------------------------------------------
// K2: proj GEMM, fp16 MFMA. C[m,e] = sum_d enc[m,d]*W[e,d] (+bias, split q/k).
// 128x128 tile, BK=32, 4 waves each 64x64 (4x4 tiles of 16x16x32).
// Staging via global_load_lds width=16 (m97 pattern): wave w stages k-chunk w
// of both tiles; LDS dest is wave-uniform base + lane*16 (linear rows).
// K rows pre-scaled by (1/8)*log2(e) so attn runs in the exp2 domain.
// ---------------------------------------------------------------------------
__global__ __launch_bounds__(256) void proj_mfma(const _Float16* __restrict__ Ah,  // [4096][1024]
                                                 const _Float16* __restrict__ Wh,  // [2048][1024]
                                                 const float* __restrict__ bias,
                                                 _Float16* __restrict__ qbuf,     // [32][2048][64]
                                                 _Float16* __restrict__ kbuf) {
    __shared__ __align__(16) _Float16 As[4][128][8];   // 8 KB
    __shared__ __align__(16) _Float16 Bs[4][128][8];   // 8 KB
    const int tid = threadIdx.x;
    const int w   = tid >> 6;
    const int l   = tid & 63;
    const int l15 = l & 15;
    const int l4  = l >> 4;
    const int wy  = w >> 1;        // 0,1 : row half
    const int wx  = w & 1;         // 0,1 : col half
    const int m0  = blockIdx.x * 128;
    const int n0  = blockIdx.y * 128;

    f32x4 acc[4][4] = {};

    for (int k0 = 0; k0 < D; k0 += 32) {
        if (k0) __syncthreads();
#if HAVE_GLDS
        {
            // wave w stages sub-chunk w (k = k0 + w*8 .. +8) for A and B.
            const _Float16* a0 = Ah + (size_t)(m0 + l) * D + k0 + w * 8;
            const _Float16* b0 = Wh + (size_t)(n0 + l) * D + k0 + w * 8;
            GLDS16(a0,            &As[w][0][0]);
            GLDS16(a0 + 64 * D,   &As[w][64][0]);
            GLDS16(b0,            &Bs[w][0][0]);
            GLDS16(b0 + 64 * D,   &Bs[w][64][0]);
        }
#else
        #pragma unroll
        for (int p = 0; p < 2; ++p) {
            const int slot = p * 256 + tid;
            const int sub = slot >> 7, row = slot & 127;
            *(uint4*)&As[sub][row][0] = *(const uint4*)(Ah + (size_t)(m0 + row) * D + k0 + sub * 8);
            *(uint4*)&Bs[sub][row][0] = *(const uint4*)(Wh + (size_t)(n0 + row) * D + k0 + sub * 8);
        }
#endif
        __syncthreads();

        half8 af[4], bf[4];
        #pragma unroll
        for (int i = 0; i < 4; ++i)
            af[i] = *(const half8*)&As[l4][wy * 64 + i * 16 + l15][0];
        #pragma unroll
        for (int j = 0; j < 4; ++j)
            bf[j] = *(const half8*)&Bs[l4][wx * 64 + j * 16 + l15][0];
        #pragma unroll
        for (int i = 0; i < 4; ++i)
            #pragma unroll
            for (int j = 0; j < 4; ++j)
                acc[i][j] = __builtin_amdgcn_mfma_f32_16x16x32_f16(af[i], bf[j], acc[i][j], 0, 0, 0);
    }

    // epilogue: e-column = n0 + wx*64 + j*16 + l15 ; m-row = m0 + wy*64 + i*16 + l4*4 + r
    #pragma unroll
    for (int j = 0; j < 4; ++j) {
        const int e   = n0 + wx * 64 + j * 16 + l15;
        const bool isq = (e < D);
        const int eh  = isq ? e : (e - D);
        const int h   = eh >> 6;
        const int hd  = eh & 63;
        _Float16* dst = isq ? qbuf : kbuf;
        const float sc = isq ? 1.0f : 0.18033688f;   // (1/8)*log2(e)
        const float bv = bias[e];
        #pragma unroll
        for (int i = 0; i < 4; ++i) {
            #pragma unroll
            for (int r = 0; r < 4; ++r) {
                const int m  = m0 + wy * 64 + i * 16 + l4 * 4 + r;
                const int bb = m >> 11;             // m / S
                const int ss = m & (S - 1);
                dst[((size_t)(bb * H + h) * S + ss) * HD + hd] = (_Float16)((acc[i][j][r] + bv) * sc);
            }
        }
    }
}

// ---------------------------------------------------------------------------
// K3: fused scores + causal softmax, no-LDS / no-barrier / no-max version.
//  - scores bounded (|s|<~6 sigma): softmax without max-subtraction is exact
//    in fp32; pass A accumulates sum(exp2(score)) in registers only.
//  - K fragments loaded half8 straight from global (L2-resident slices).
//  - diagonal tile handled outside the hot loops (no per-iter mask branch).
//  - 1-D grid of 1024: each XCD owns 4 heads; each CU's 4 resident blocks
//    have stripe weights summing to a constant 66 tile-iters.
//  - __launch_bounds__(256,4) pins VGPR<=128 so all 4 blocks/CU co-reside.
//  - all output stores nontemporal (512 MiB stream must not evict K/Q).
// ---------------------------------------------------------------------------
__global__ __launch_bounds__(256, 4) void attn_fused(const _Float16* __restrict__ qbuf,
                                                     const _Float16* __restrict__ kbuf,
                                                     float* __restrict__ out) {
    const int tid = threadIdx.x;
    const int w   = tid >> 6;
    const int l   = tid & 63;
    const int l15 = l & 15;
    const int l4  = l >> 4;

    // block remap: bid -> (z, t-stripe)
    const int bid  = blockIdx.x;        // 0..1023
    const int xcd  = bid & 7;
    const int slot = bid >> 3;          // 0..127
    const int k    = slot >> 5;         // 0..3 : which of this XCD's 4 heads
    int tsr = slot & 31;
    if (k & 2) tsr = (tsr + 16) & 31;
    const int ts = (k & 1) ? (31 - tsr) : tsr;   // stripe 0..31, CU-balanced
    const int z  = xcd * 4 + k;                  // 0..31 = b*H+h
    const int t0 = ts * 64;

    const _Float16* Qg = qbuf + (size_t)z * S * HD;
    const _Float16* Kg = kbuf + (size_t)z * S * HD;
    float* outz = out + (size_t)z * S * S;

    // Q fragments: rows t0 + w*16 + l15, halves [l4*8, +8) and [32+l4*8, +8)
    const _Float16* qrow = Qg + (size_t)(t0 + w * 16 + l15) * HD + l4 * 8;
    const half8 qf0 = *(const half8*)qrow;
    const half8 qf1 = *(const half8*)(qrow + 32);

    const int trow = t0 + w * 16 + l4 * 4;
    const _Float16* kbase = Kg + (size_t)l15 * HD + l4 * 8;

    float sum_r[4] = {0.f, 0.f, 0.f, 0.f};

    // ---------------- PASS A: row sums of exp2(score) ----------------
    for (int st = 0; st < ts; ++st) {          // full (unmasked) tiles
        const _Float16* kp = kbase + (size_t)st * (64 * HD);
        f32x4 c[4] = {};
        #pragma unroll
        for (int j = 0; j < 4; ++j) {
            const half8 kf0 = *(const half8*)(kp + j * (16 * HD));
            const half8 kf1 = *(const half8*)(kp + j * (16 * HD) + 32);
            c[j] = __builtin_amdgcn_mfma_f32_16x16x32_f16(qf0, kf0, c[j], 0, 0, 0);
            c[j] = __builtin_amdgcn_mfma_f32_16x16x32_f16(qf1, kf1, c[j], 0, 0, 0);
        }
        #pragma unroll
        for (int j = 0; j < 4; ++j)
            #pragma unroll
            for (int r = 0; r < 4; ++r)
                sum_r[r] += fast_exp2(c[j][r]);
    }
    {   // diagonal tile (st == ts): mask s > t
        const _Float16* kp = kbase + (size_t)ts * (64 * HD);
        f32x4 c[4] = {};
        #pragma unroll
        for (int j = 0; j < 4; ++j) {
            const half8 kf0 = *(const half8*)(kp + j * (16 * HD));
            const half8 kf1 = *(const half8*)(kp + j * (16 * HD) + 32);
            c[j] = __builtin_amdgcn_mfma_f32_16x16x32_f16(qf0, kf0, c[j], 0, 0, 0);
            c[j] = __builtin_amdgcn_mfma_f32_16x16x32_f16(qf1, kf1, c[j], 0, 0, 0);
        }
        #pragma unroll
        for (int j = 0; j < 4; ++j) {
            const int scol = t0 + j * 16 + l15;
            #pragma unroll
            for (int r = 0; r < 4; ++r) {
                if (scol > trow + r) c[j][r] = -1e30f;   // exp2 -> exact 0
                sum_r[r] += fast_exp2(c[j][r]);
            }
        }
    }

    // single cross-lane reduce per block (16-lane groups share rows)
    float inv_l[4];
    #pragma unroll
    for (int r = 0; r < 4; ++r) {
        float s = sum_r[r];
        s += __shfl_xor(s, 1, 16);
        s += __shfl_xor(s, 2, 16);
        s += __shfl_xor(s, 4, 16);
        s += __shfl_xor(s, 8, 16);
        inv_l[r] = 1.0f / s;
    }

    // ---------------- PASS B: recompute + write ----------------
    float* wrow = outz + (size_t)trow * S + l15;
    for (int st = 0; st < ts; ++st) {          // full tiles
        const int s0 = st * 64;
        const _Float16* kp = kbase + (size_t)st * (64 * HD);
        f32x4 c[4] = {};
        #pragma unroll
        for (int j = 0; j < 4; ++j) {
            const half8 kf0 = *(const half8*)(kp + j * (16 * HD));
            const half8 kf1 = *(const half8*)(kp + j * (16 * HD) + 32);
            c[j] = __builtin_amdgcn_mfma_f32_16x16x32_f16(qf0, kf0, c[j], 0, 0, 0);
            c[j] = __builtin_amdgcn_mfma_f32_16x16x32_f16(qf1, kf1, c[j], 0, 0, 0);
        }
        #pragma unroll
        for (int r = 0; r < 4; ++r) {
            float* rowp = wrow + (size_t)r * S + s0;
            #pragma unroll
            for (int j = 0; j < 4; ++j)
                __builtin_nontemporal_store(fast_exp2(c[j][r]) * inv_l[r], rowp + j * 16);
        }
    }
    {   // diagonal tile
        const int s0 = ts * 64;
        const _Float16* kp = kbase + (size_t)ts * (64 * HD);
        f32x4 c[4] = {};
        #pragma unroll
        for (int j = 0; j < 4; ++j) {
            const half8 kf0 = *(const half8*)(kp + j * (16 * HD));
            const half8 kf1 = *(const half8*)(kp + j * (16 * HD) + 32);
            c[j] = __builtin_amdgcn_mfma_f32_16x16x32_f16(qf0, kf0, c[j], 0, 0, 0);
            c[j] = __builtin_amdgcn_mfma_f32_16x16x32_f16(qf1, kf1, c[j], 0, 0, 0);
        }
        #pragma unroll
        for (int j = 0; j < 4; ++j) {
            const int scol = t0 + j * 16 + l15;
            #pragma unroll
            for (int r = 0; r < 4; ++r)
                if (scol > trow + r) c[j][r] = -1e30f;
        }
        #pragma unroll
        for (int r = 0; r < 4; ++r) {
            float* rowp = wrow + (size_t)r * S + s0;
            #pragma unroll
            for (int j = 0; j < 4; ++j)
                __builtin_nontemporal_store(fast_exp2(c[j][r]) * inv_l[r], rowp + j * 16);
        }
    }

    // ---------------- zero-fill upper-triangle rectangle ----------------
    const int zc0 = t0 + 64;            // cols [zc0, S) are zero for all 64 rows
    if (zc0 < S) {
        const int W4 = (S - zc0) >> 2;
        const f32x4 z4 = {0.f, 0.f, 0.f, 0.f};
        for (int row = w; row < 64; row += 4) {       // per-wave rows: no barrier needed
            float* rp = outz + (size_t)(t0 + row) * S + zc0;
            for (int c4 = l; c4 < W4; c4 += 64)
                __builtin_nontemporal_store(z4, (f32x4*)(rp + c4 * 4));
        }
    }
}

extern "C" void kernel_launch(void* const* d_in, const int* in_sizes, int n_in,
                              void* d_out, int out_size, void* d_ws, size_t ws_size,
                              hipStream_t stream) {
    const float* enc  = (const float*)d_in[0];   // (2,2048,1024) fp32
    const float* Wf   = (const float*)d_in[1];   // (2048,1024)   fp32
    const float* bias = (const float*)d_in[2];   // (2048,)       fp32
    float* out = (float*)d_out;                  // (2,16,2048,2048) fp32

    _Float16* enc_h = (_Float16*)d_ws;                       // 4,194,304 elems
    _Float16* w_h   = enc_h + (size_t)4096 * 1024;           // 2,097,152
    _Float16* qbuf  = w_h   + (size_t)2048 * 1024;           // 4,194,304
    _Float16* kbuf  = qbuf  + (size_t)32 * 2048 * 64;        // 4,194,304

    const int n4_total = N4_ENC + N4_W;                      // 1,572,864
    cvt_both<<<(n4_total + 255) / 256, 256, 0, stream>>>(enc, Wf, enc_h, w_h);

    proj_mfma<<<dim3(4096 / 128, 2048 / 128), 256, 0, stream>>>(enc_h, w_h, bias, qbuf, kbuf);

    attn_fused<<<dim3(1024), 256, 0, stream>>>(qbuf, kbuf, out);
}